// Round 9
// baseline (162.314 us; speedup 1.0000x reference)
//
#include <hip/hip_runtime.h>
#include <hip/hip_bf16.h>
#include <stdint.h>

#define B_  2
#define S_  2048
#define H_  512
#define NH_ 8
#define DK_ 64

typedef __bf16 bf16x8 __attribute__((ext_vector_type(8)));
typedef short  s16x4  __attribute__((ext_vector_type(4)));
typedef float  f32x4  __attribute__((ext_vector_type(4)));

static __device__ __forceinline__ uint32_t pk2(float a, float b) {
  __hip_bfloat162 h = __float22bfloat162_rn(float2{a, b});
  uint32_t u;
  __builtin_memcpy(&u, &h, 4);
  return u;
}

// 16x16x16 bf16 MFMA. Guard with __HIP_DEVICE_COMPILE__ (host pass lacks
// device builtins — R3 compile failure).
static __device__ __forceinline__ f32x4 mfma_k16(s16x4 a, s16x4 b, f32x4 c) {
#if defined(__HIP_DEVICE_COMPILE__)
  return __builtin_amdgcn_mfma_f32_16x16x16bf16_1k(a, b, c, 0, 0, 0);
#else
  (void)a; (void)b;
  return c;
#endif
}

typedef const __attribute__((address_space(1))) uint32_t* gas_t;
typedef __attribute__((address_space(3))) uint32_t* las_t;
static __device__ __forceinline__ void cp16(const void* g, void* l) {
  __builtin_amdgcn_global_load_lds((gas_t)g, (las_t)l, 16, 0, 0);
}

// ---------------------------------------------------------------------------
// Kernel 1 (fused): proj (blocks 0..1535, 64x64 tiles, XCD-swizzled so all 8
// dtile-blocks of one (mat,mtile) share one XCD's L2 copy of the X tile) +
// bias zero-scan (1536..2047) + fmL (2048).
// R8->R9: tile 128x64 -> 64x64 doubles resident blocks/CU (3 -> 6+) so the
// ~800-cycle per-iter staging latency is covered by cross-block overlap
// (register-prefetch only hides ~100 cycles of it).
// ---------------------------------------------------------------------------
struct ProjArgs {
  const float* X[3];
  const float* W[3];
  const float* Bv[3];
  uint16_t*    O[3];
  const float* bias;
  const int*   mask;
  uint32_t*    zrow;
  float*       fmL;
};

__global__ __launch_bounds__(256) void prep_proj_kernel(ProjArgs pa) {
  __shared__ __align__(16) char psm[16512];
  int bid = blockIdx.x, t = threadIdx.x;

  if (bid >= 1536) {
    if (bid < 2048) {
      // ---- bias zero-scan: 8 (b,q) rows per block, loads pipelined ----
      int rr = bid - 1536;                     // 0..511
      const float* base = pa.bias + (size_t)rr * 8 * 2048 + t * 8;
      uint4 a[8], b2[8];
#pragma unroll
      for (int i = 0; i < 8; i++) {
        const uint4* src = (const uint4*)(base + (size_t)i * 2048);
        a[i] = src[0]; b2[i] = src[1];
      }
      uint32_t (*wbuf)[4] = (uint32_t (*)[4])psm;   // [row][wave]
      int wv = t >> 6, ln = t & 63;
#pragma unroll
      for (int i = 0; i < 8; i++) {
        bool z = ((a[i].x << 1) == 0u) | ((a[i].y << 1) == 0u) |
                 ((a[i].z << 1) == 0u) | ((a[i].w << 1) == 0u) |
                 ((b2[i].x << 1) == 0u) | ((b2[i].y << 1) == 0u) |
                 ((b2[i].z << 1) == 0u) | ((b2[i].w << 1) == 0u);
        uint64_t m = __ballot(z);
        if (ln == 0) {
          uint32_t bits = 0;
#pragma unroll
          for (int c = 0; c < 8; c++)
            bits |= (uint32_t)(((m >> (8 * c)) & 0xFFull) != 0ull) << c;
          wbuf[i][wv] = bits;                  // chunks [wv*8, wv*8+8)
        }
      }
      __syncthreads();
      if (t < 8)
        pa.zrow[rr * 8 + t] = wbuf[t][0] | (wbuf[t][1] << 8) |
                              (wbuf[t][2] << 16) | (wbuf[t][3] << 24);
    } else {
      // ---- fmL = mask * log2(e) ----
      const float LOG2E = 1.44269504088896340736f;
#pragma unroll
      for (int i = 0; i < 16; i++) {
        int idx = i * 256 + t;
        pa.fmL[idx] = (float)pa.mask[idx] * LOG2E;
      }
    }
    return;
  }

  // ---- proj: y = x @ W^T + b, tile 64 s x 64 d, 1536 blocks ----
  // XCD swizzle: all 8 dtiles of group gi=(mat,mtile) share bid%8 -> one XCD.
  int xcd = bid & 7, j = bid >> 3;             // j in 0..191
  int gi = ((j >> 3) << 3) | xcd;              // group 0..191
  int dtile = j & 7;
  int mat = gi >> 6, mtile = gi & 63;
  int m0 = mtile * 64, n0 = dtile * 64;
  const float* X  = pa.X[mat];
  const float* Wt = pa.W[mat];
  const float* Bv = pa.Bv[mat];
  uint16_t*    O  = pa.O[mat];

  uint16_t (*Xs)[64] = (uint16_t (*)[64])psm;            // [64][64] 8 KB
  uint16_t (*Ws)[64] = (uint16_t (*)[64])(psm + 8192);   // [64][64] 8 KB

  int w = t >> 6, l = t & 63, lo = l & 15, g = l >> 4;
  int tr = t >> 4;          // 0..15 row-in-pass (16 lanes per row)
  int lc = t & 15;          // 16B column chunk within the 256B row segment

  // coalesced staging bases: lane covers float cols [lc*4, lc*4+4)
  const float* Xp = X + (size_t)(m0 + tr) * 512 + lc * 4;
  const float* Wp = Wt + (size_t)(n0 + tr) * 512 + lc * 4;

  f32x4 acc[4];
#pragma unroll
  for (int dt = 0; dt < 4; dt++) acc[dt] = (f32x4){0.f, 0.f, 0.f, 0.f};

  float4 xa[4], wa2[4];
#pragma unroll
  for (int i = 0; i < 4; i++) {
    xa[i]  = *(const float4*)(Xp + (size_t)i * 16 * 512);
    wa2[i] = *(const float4*)(Wp + (size_t)i * 16 * 512);
  }

  for (int kb = 0; kb < 8; kb++) {
    // pack current registers -> LDS (bf16), b64 per row-chunk.
    // Layout: row-major, 16B segs XOR'd by row&7 (2-way bank alias = free).
#pragma unroll
    for (int i = 0; i < 4; i++) {
      int r = i * 16 + tr;
      int s0 = (lc >> 1) ^ (r & 7);
      uint2 pkx{pk2(xa[i].x, xa[i].y), pk2(xa[i].z, xa[i].w)};
      *(uint2*)&Xs[r][s0 * 8 + (lc & 1) * 4] = pkx;
      uint2 pkw{pk2(wa2[i].x, wa2[i].y), pk2(wa2[i].z, wa2[i].w)};
      *(uint2*)&Ws[r][s0 * 8 + (lc & 1) * 4] = pkw;
    }
    __syncthreads();
    if (kb < 7) {
      const float* Xn = Xp + (kb + 1) * 64;
      const float* Wn = Wp + (kb + 1) * 64;
#pragma unroll
      for (int i = 0; i < 4; i++) {
        xa[i]  = *(const float4*)(Xn + (size_t)i * 16 * 512);
        wa2[i] = *(const float4*)(Wn + (size_t)i * 16 * 512);
      }
    }
#pragma unroll
    for (int kk = 0; kk < 2; kk++) {
      int seg = (kk * 4 + g) ^ (lo & 7);
      bf16x8 xf = *(const bf16x8*)&Xs[w * 16 + lo][seg * 8];
      bf16x8 wf[4];
#pragma unroll
      for (int dt = 0; dt < 4; dt++)
        wf[dt] = *(const bf16x8*)&Ws[dt * 16 + lo][seg * 8];
      if (mat < 2) {
#pragma unroll
        for (int dt = 0; dt < 4; dt++)
          acc[dt] = __builtin_amdgcn_mfma_f32_16x16x32_bf16(wf[dt], xf, acc[dt], 0, 0, 0);
      } else {
#pragma unroll
        for (int dt = 0; dt < 4; dt++)
          acc[dt] = __builtin_amdgcn_mfma_f32_16x16x32_bf16(xf, wf[dt], acc[dt], 0, 0, 0);
      }
    }
    __syncthreads();
  }

  if (mat < 2) {
    // C: row = d-local = g*4+r, col = s-local = lo -> 4 consecutive d / lane
    float scale = (mat == 0) ? 0.125f : 1.0f;
    float4 bv4[4];
#pragma unroll
    for (int dt = 0; dt < 4; dt++)
      bv4[dt] = *(const float4*)(Bv + n0 + dt * 16 + g * 4);
    int ss = m0 + w * 16 + lo;
    int bb = ss >> 11, sIn = ss & 2047;
    uint16_t* obase = O + ((size_t)(bb * NH_ + dtile) * S_ + sIn) * DK_;
#pragma unroll
    for (int dt = 0; dt < 4; dt++) {
      float v0 = (acc[dt][0] + bv4[dt].x) * scale;
      float v1 = (acc[dt][1] + bv4[dt].y) * scale;
      float v2 = (acc[dt][2] + bv4[dt].z) * scale;
      float v3 = (acc[dt][3] + bv4[dt].w) * scale;
      uint2 pk{pk2(v0, v1), pk2(v2, v3)};
      *(uint2*)(obase + dt * 16 + g * 4) = pk;
    }
  } else {
    // C: row = s-local = g*4+r, col = d-local = lo -> 4 consecutive s / lane
    float bval[4];
#pragma unroll
    for (int dt = 0; dt < 4; dt++) bval[dt] = Bv[n0 + dt * 16 + lo];
    int m = m0 + w * 16 + g * 4;
    int bb = m >> 11, sIn = m & 2047;
#pragma unroll
    for (int dt = 0; dt < 4; dt++) {
      int dd = dt * 16 + lo;
      float v0 = acc[dt][0] + bval[dt];
      float v1 = acc[dt][1] + bval[dt];
      float v2 = acc[dt][2] + bval[dt];
      float v3 = acc[dt][3] + bval[dt];
      uint2 pk{pk2(v0, v1), pk2(v2, v3)};
      *(uint2*)(O + ((size_t)(bb * NH_ + dtile) * DK_ + dd) * S_ + sIn) = pk;
    }
  }
}

// ---------------------------------------------------------------------------
// Kernel 2: flash attention (unchanged — verified, 41 µs @ R8). 256 thr,
// 4 waves, k-tile 64, q-tile 32 -> grid 1024 -> 4 blocks/CU, no spills.
// R5 lesson: never buy occupancy with a VGPR cap below the live footprint.
// ---------------------------------------------------------------------------
__global__ __launch_bounds__(256, 2) void attn_kernel(
    const uint16_t* __restrict__ Qb, const uint16_t* __restrict__ Kb,
    const uint16_t* __restrict__ Vt, const uint32_t* __restrict__ zrow,
    const float* __restrict__ fmL, const float* __restrict__ bias,
    float* __restrict__ out) {
  int bid = blockIdx.x;
  int bh = bid & 15, qtile = bid >> 4;   // bid%8 const per bh -> same XCD
  int b = bh >> 3, h = bh & 7;
  int q0 = qtile * 32;
  int t = threadIdx.x;
  int w = t >> 6, l = t & 63, lo = l & 15, g = l >> 4;

  __shared__ __align__(16) char smem[32768];
  uint16_t* KsB = (uint16_t*)smem;             // [2][64 k][64 d] 16 KB
  uint16_t* VsB = (uint16_t*)(smem + 16384);   // [2][64 d][64 k] 16 KB

  const uint16_t* Qh = Qb + (size_t)bh * S_ * DK_;
  const uint16_t* Kh = Kb + (size_t)bh * S_ * DK_;
  const uint16_t* Vh = Vt + (size_t)bh * DK_ * S_;

  // DMA: lane l -> LDS row w*16 + l/8, seg l&7; global seg = (l&7)^(row&7).
  int lrow = l >> 3, lseg = (l & 7) ^ lrow;
  const uint16_t* kbase = Kh + (size_t)(w * 16 + lrow) * DK_ + lseg * 8;
  const uint16_t* vbase = Vh + (size_t)(w * 16 + lrow) * S_ + lseg * 8;
  uint16_t* kd0 = KsB + (w * 16) * 64;
  uint16_t* kd8 = KsB + (w * 16 + 8) * 64;
  uint16_t* vd0 = VsB + (w * 16) * 64;
  uint16_t* vd8 = VsB + (w * 16 + 8) * 64;

  // block-uniform zero-bias mask (OR over this block's 32 q rows)
  uint32_t zall = zrow[(b << 11) + q0 + (l & 31)];
#pragma unroll
  for (int s = 1; s < 32; s <<= 1) zall |= __shfl_xor(zall, s);

  // Register-resident Q fragments (B-operand of QK), 2 q-subtiles x K=64.
  bf16x8 qf[2][2];
#pragma unroll
  for (int qt = 0; qt < 2; qt++)
#pragma unroll
    for (int kk = 0; kk < 2; kk++)
      qf[qt][kk] = *(const bf16x8*)(Qh + (size_t)(q0 + qt * 16 + lo) * DK_ + kk * 32 + g * 8);

  f32x4 o[4][2];
#pragma unroll
  for (int dt = 0; dt < 4; dt++)
#pragma unroll
    for (int qt = 0; qt < 2; qt++) o[dt][qt] = (f32x4){0.f, 0.f, 0.f, 0.f};
  float ts[2] = {0.f, 0.f};

  const float* fmrow = fmL + b * S_ + w * 16 + g * 4;
  const float LOG2E = 1.44269504088896340736f;

  // stage tile 0
  cp16(kbase, kd0);
  cp16(kbase + 512, kd8);
  cp16(vbase, vd0);
  cp16(vbase + 8 * S_, vd8);

  for (int kb = 0; kb < 32; kb++) {
    int cur = kb & 1;
    int k0 = kb * 64;
    float4 mv4 = *(const float4*)(fmrow + k0);
    __syncthreads();                             // drains DMA for tile kb
    if (kb + 1 < 32) {                           // prefetch tile kb+1
      int kn = k0 + 64;
      int nb = (cur ^ 1) * 4096;
      cp16(kbase + (size_t)kn * 64, kd0 + nb);
      cp16(kbase + (size_t)kn * 64 + 512, kd8 + nb);
      cp16(vbase + kn, vd0 + nb);
      cp16(vbase + kn + 8 * S_, vd8 + nb);
    }
    const uint16_t* KsT = KsB + cur * 4096;
    const uint16_t* VsT = VsB + cur * 4096;

    // V^T A-frags for PV
    s16x4 vf[4];
    {
      int s = (2 * w + (g >> 1)) ^ (lo & 7);
      int off = s * 8 + (g & 1) * 4;
#pragma unroll
      for (int dt = 0; dt < 4; dt++)
        vf[dt] = *(const s16x4*)(VsT + (dt * 16 + lo) * 64 + off);
    }
    // K A-frags (this wave's 16 k-rows)
    bf16x8 kf[2];
#pragma unroll
    for (int kk = 0; kk < 2; kk++) {
      int s = (kk * 4 + g) ^ (lo & 7);
      kf[kk] = *(const bf16x8*)(KsT + (w * 16 + lo) * 64 + s * 8);
    }

    // S^T = K * Q^T : lane holds S[k = w*16+g*4+r][q = qt*16+lo]
    f32x4 c[2];
#pragma unroll
    for (int qt = 0; qt < 2; qt++) {
      f32x4 z = {0.f, 0.f, 0.f, 0.f};
      z = __builtin_amdgcn_mfma_f32_16x16x32_bf16(kf[0], qf[qt][0], z, 0, 0, 0);
      c[qt] = __builtin_amdgcn_mfma_f32_16x16x32_bf16(kf[1], qf[qt][1], z, 0, 0, 0);
    }

    float p[2][4];
    if (((zall >> kb) & 1u) == 0u) {   // no zero bias in this 64k chunk
#pragma unroll
      for (int qt = 0; qt < 2; qt++) {
        p[qt][0] = __builtin_amdgcn_exp2f(__builtin_fmaf(c[qt][0], LOG2E, mv4.x));
        p[qt][1] = __builtin_amdgcn_exp2f(__builtin_fmaf(c[qt][1], LOG2E, mv4.y));
        p[qt][2] = __builtin_amdgcn_exp2f(__builtin_fmaf(c[qt][2], LOG2E, mv4.z));
        p[qt][3] = __builtin_amdgcn_exp2f(__builtin_fmaf(c[qt][3], LOG2E, mv4.w));
      }
    } else {                           // rare: bias==0 -> weight 0
#pragma unroll
      for (int qt = 0; qt < 2; qt++) {
        float4 bz = *(const float4*)(bias + ((size_t)(b * S_ + q0 + qt * 16 + lo)) * S_ + k0 + w * 16 + g * 4);
        p[qt][0] = (bz.x == 0.f) ? 0.f : __builtin_amdgcn_exp2f(__builtin_fmaf(c[qt][0], LOG2E, mv4.x));
        p[qt][1] = (bz.y == 0.f) ? 0.f : __builtin_amdgcn_exp2f(__builtin_fmaf(c[qt][1], LOG2E, mv4.y));
        p[qt][2] = (bz.z == 0.f) ? 0.f : __builtin_amdgcn_exp2f(__builtin_fmaf(c[qt][2], LOG2E, mv4.z));
        p[qt][3] = (bz.w == 0.f) ? 0.f : __builtin_amdgcn_exp2f(__builtin_fmaf(c[qt][3], LOG2E, mv4.w));
      }
    }

    s16x4 pf[2];
#pragma unroll
    for (int qt = 0; qt < 2; qt++) {
      ts[qt] += (p[qt][0] + p[qt][1]) + (p[qt][2] + p[qt][3]);
      union { s16x4 v; uint32_t u[2]; } uu;
      uu.u[0] = pk2(p[qt][0], p[qt][1]);
      uu.u[1] = pk2(p[qt][2], p[qt][3]);
      pf[qt] = uu.v;
    }

    // PV: o[dt][qt] lane holds O[q=qt*16+lo][d=dt*16+g*4+r]
#pragma unroll
    for (int dt = 0; dt < 4; dt++)
#pragma unroll
      for (int qt = 0; qt < 2; qt++)
        o[dt][qt] = mfma_k16(vf[dt], pf[qt], o[dt][qt]);
  }

  // ---- epilogue: reduce 4 wave-partials, normalize, store ----
  float* OT = (float*)smem;               // [64 d][33] floats (8448 B)
  float* LS = (float*)(smem + 8448);      // [4 w][2 qt][16 lo]
#pragma unroll
  for (int qt = 0; qt < 2; qt++) {
    float v = ts[qt];
    v += __shfl_xor(v, 16);
    v += __shfl_xor(v, 32);
    ts[qt] = v;
  }
  __syncthreads();                        // main-loop LDS reads complete
  if (g == 0) {
#pragma unroll
    for (int qt = 0; qt < 2; qt++) LS[(w * 2 + qt) * 16 + lo] = ts[qt];
  }
#pragma unroll
  for (int ww = 0; ww < 4; ww++) {
    if (w == ww) {
#pragma unroll
      for (int dt = 0; dt < 4; dt++)
#pragma unroll
        for (int qt = 0; qt < 2; qt++)
#pragma unroll
          for (int r = 0; r < 4; r++) {
            int idx = (dt * 16 + g * 4 + r) * 33 + qt * 16 + lo;
            if (ww == 0) OT[idx] = o[dt][qt][r];
            else         OT[idx] += o[dt][qt][r];
          }
    }
    __syncthreads();
  }
  {
    int q = t >> 3, dseg = (t & 7) * 8;   // q in [0,32), 8 d per thread
    int qt2 = q >> 4, lo2 = q & 15;
    float lsum = LS[(0 * 2 + qt2) * 16 + lo2] + LS[(1 * 2 + qt2) * 16 + lo2] +
                 LS[(2 * 2 + qt2) * 16 + lo2] + LS[(3 * 2 + qt2) * 16 + lo2];
    float linv = 1.0f / fmaxf(lsum, 1e-30f);
    float* ob = out + ((size_t)(b * S_ + q0 + q)) * H_ + h * DK_ + dseg;
#pragma unroll
    for (int i = 0; i < 2; i++) {
      float4 v;
      v.x = OT[(dseg + i * 4 + 0) * 33 + q] * linv;
      v.y = OT[(dseg + i * 4 + 1) * 33 + q] * linv;
      v.z = OT[(dseg + i * 4 + 2) * 33 + q] * linv;
      v.w = OT[(dseg + i * 4 + 3) * 33 + q] * linv;
      *(float4*)(ob + i * 4) = v;
    }
  }
}

// ---------------------------------------------------------------------------
extern "C" void kernel_launch(void* const* d_in, const int* in_sizes, int n_in,
                              void* d_out, int out_size, void* d_ws, size_t ws_size,
                              hipStream_t stream) {
  const float* query = (const float*)d_in[0];
  const float* key   = (const float*)d_in[1];
  const float* value = (const float*)d_in[2];
  const float* bias  = (const float*)d_in[3];
  const int*   mask  = (const int*)d_in[4];
  const float* Wq = (const float*)d_in[5];
  const float* bq = (const float*)d_in[6];
  const float* Wk = (const float*)d_in[7];
  const float* bk = (const float*)d_in[8];
  const float* Wv = (const float*)d_in[9];
  const float* bv = (const float*)d_in[10];

  char* ws = (char*)d_ws;
  uint32_t* zrow = (uint32_t*)ws;                             // 16 KB
  float*    fmL  = (float*)(ws + 16384);                      // 16 KB
  uint16_t* Qb = (uint16_t*)(ws + (size_t)(1 << 20));         // 4 MB
  uint16_t* Kb = (uint16_t*)(ws + (size_t)(5 << 20));         // 4 MB
  uint16_t* Vt = (uint16_t*)(ws + (size_t)(9 << 20));         // 4 MB

  ProjArgs pa;
  pa.X[0] = query; pa.X[1] = key; pa.X[2] = value;
  pa.W[0] = Wq;    pa.W[1] = Wk;  pa.W[2] = Wv;
  pa.Bv[0] = bq;   pa.Bv[1] = bk; pa.Bv[2] = bv;
  pa.O[0] = Qb;    pa.O[1] = Kb;  pa.O[2] = Vt;
  pa.bias = bias;  pa.mask = mask;
  pa.zrow = zrow;  pa.fmL = fmL;

  prep_proj_kernel<<<2049, 256, 0, stream>>>(pa);

  attn_kernel<<<1024, 256, 0, stream>>>(Qb, Kb, Vt, zrow, fmL, bias, (float*)d_out);
}